// Round 5
// baseline (270.294 us; speedup 1.0000x reference)
//
#include <hip/hip_runtime.h>
#include <stdint.h>

#define BATCH   32
#define ROWS    4096
#define COLS    256
#define COL_IDX 5

typedef unsigned long long u64;
typedef unsigned int       u32;

// ---------------------------------------------------------------------------
// Kernel 1: extract column COL_IDX, pack into order-preserving u64 keys.
//   hi 32 = ~(order_preserving_uint(f))  -> ascending u64 == descending float
//   lo 32 = row index                    -> distinct keys, stable tie-break
// ---------------------------------------------------------------------------
__global__ __launch_bounds__(256)
void extract_keys_kernel(const float* __restrict__ x, u64* __restrict__ keys) {
    const int i = blockIdx.x * 256 + threadIdx.x;      // 0 .. BATCH*ROWS-1
    u32 u = __float_as_uint(x[(size_t)i * COLS + COL_IDX]);
    u = (u >> 31) ? ~u : (u | 0x80000000u);            // order-preserving map
    u = ~u;                                            // descending
    keys[i] = ((u64)u << 32) | (u32)(i & (ROWS - 1));
}

// ---------------------------------------------------------------------------
// Kernel 2: ballot-rank only (R4 LESSON: fusing rank+copy serializes a
// latency chain and forces the copy to run at rank's low occupancy — all
// counters <30% saturated). Block owns 64 rows; each of 4 waves holds a
// 1024-key quarter in registers and counts keys < key_m via
// v_cmp_lt_u64 -> ballot -> s_bcnt1 (SALU pipe). Output: absolute output
// row index per source row (4 B each, 512 KB total).
// ---------------------------------------------------------------------------
__global__ __launch_bounds__(256)
void rank_kernel(const u64* __restrict__ keys, u32* __restrict__ dstg) {
    __shared__ int part[4][64];
    const int w    = (int)threadIdx.x >> 6;     // wave in block (0..3)
    const int lane = (int)threadIdx.x & 63;
    const int b    = blockIdx.x >> 6;           // 64 blocks per batch
    const int r0   = (blockIdx.x & 63) << 6;    // block's first row
    const u64* __restrict__ kb = keys + (size_t)b * ROWS;

    const int jbeg = w * (ROWS / 4);
    u64 kv[16];
    #pragma unroll
    for (int t = 0; t < 16; ++t)
        kv[t] = kb[jbeg + t * 64 + lane];
    const u64 my = kb[r0 + lane];

    const u32 my_lo = (u32)my, my_hi = (u32)(my >> 32);
    int vrank = 0;
    #pragma unroll 2
    for (int m = 0; m < 64; ++m) {
        const u32 klo = (u32)__builtin_amdgcn_readlane((int)my_lo, m);
        const u32 khi = (u32)__builtin_amdgcn_readlane((int)my_hi, m);
        const u64 mym = ((u64)khi << 32) | klo;
        int rank_m = 0;
        #pragma unroll
        for (int t = 0; t < 16; ++t)
            rank_m += (int)__popcll(__ballot(kv[t] < mym));
        vrank = (lane == m) ? rank_m : vrank;   // uniform rank_m -> lane m
    }

    part[w][lane] = vrank;
    __syncthreads();
    if (w == 0) {
        const int total = part[0][lane] + part[1][lane]
                        + part[2][lane] + part[3][lane];
        dstg[(size_t)b * ROWS + r0 + lane] = (u32)(b * ROWS) + (u32)total;
    }
}

// ---------------------------------------------------------------------------
// Kernel 3: pure streaming scatter-copy. One row per wave-step: 1 KB
// contiguous read + 1 KB contiguous write, no LDS, no barrier, ~16 VGPR ->
// full occupancy. This is the 256 MiB BW-bound phase, now running at max
// parallelism instead of under the rank kernel's 2-blocks/CU regime.
// ---------------------------------------------------------------------------
__global__ __launch_bounds__(256)
void scatter_copy_kernel(const float* __restrict__ x,
                         const u32* __restrict__ dstg,
                         float* __restrict__ out) {
    const int w    = (int)threadIdx.x >> 6;
    const int lane = (int)threadIdx.x & 63;
    const int rg0  = blockIdx.x * 16 + w * 4;   // 16 rows/block, 4/wave
    const float4* __restrict__ src = (const float4*)x;
    float4* __restrict__ o = (float4*)out;
    #pragma unroll
    for (int t = 0; t < 4; ++t) {
        const int rg  = rg0 + t;
        const u32 dg  = dstg[rg];               // uniform per wave-iter
        o[(size_t)dg * 64 + lane] = src[(size_t)rg * 64 + lane];
    }
}

extern "C" void kernel_launch(void* const* d_in, const int* in_sizes, int n_in,
                              void* d_out, int out_size, void* d_ws, size_t ws_size,
                              hipStream_t stream) {
    const float* x   = (const float*)d_in[0];
    float*       out = (float*)d_out;
    u64*         keys = (u64*)d_ws;                       // 1 MB
    u32*         dstg = (u32*)((char*)d_ws + (size_t)BATCH * ROWS * 8); // +512 KB

    extract_keys_kernel<<<(BATCH * ROWS) / 256, 256, 0, stream>>>(x, keys);
    rank_kernel<<<BATCH * 64, 256, 0, stream>>>(keys, dstg);
    scatter_copy_kernel<<<(BATCH * ROWS) / 16, 256, 0, stream>>>(x, dstg, out);
}